// Round 9
// baseline (87.856 us; speedup 1.0000x reference)
//
#include <hip/hip_runtime.h>
#include <hip/hip_bf16.h>
#include <math.h>

#define NN 1000000
#define F 128
#define N0 16384
#define N1 4096
#define HS0 65536
#define HS1 16384

typedef __attribute__((ext_vector_type(8))) short bf16x8;
typedef __attribute__((ext_vector_type(4))) float f32x4;

__device__ inline unsigned short f2b(float f) {
    union { float f; unsigned u; } v; v.f = f;
    unsigned r = v.u + 0x7FFFu + ((v.u >> 16) & 1u);
    return (unsigned short)(r >> 16);
}

__device__ inline bf16x8 pack8(float4 a, float4 b) {
    union { __hip_bfloat162 h2[4]; bf16x8 v; } u;
    u.h2[0] = __float22bfloat162_rn(make_float2(a.x, a.y));
    u.h2[1] = __float22bfloat162_rn(make_float2(a.z, a.w));
    u.h2[2] = __float22bfloat162_rn(make_float2(b.x, b.y));
    u.h2[3] = __float22bfloat162_rn(make_float2(b.z, b.w));
    return u.v;
}

__device__ inline uint2 pack4(float4 a) {
    union { __hip_bfloat162 h2[2]; uint2 v; } u;
    u.h2[0] = __float22bfloat162_rn(make_float2(a.x, a.y));
    u.h2[1] = __float22bfloat162_rn(make_float2(a.z, a.w));
    return u.v;
}

// k-permutation: storage position p -> source element pi(p), p in [0,128).
__device__ inline int kperm(int p) {
    int kk = p >> 5, kg = (p >> 3) & 3, e = p & 7;
    return kk * 32 + kg * 4 + (e < 4 ? e : e + 12);
}

// ---------------- open-addressing hash (last-occurrence-wins) ----------------

__device__ inline void hins(unsigned* __restrict__ keys, unsigned* __restrict__ vals,
                            unsigned mask, unsigned g, unsigned pos1) {
    unsigned s = (g * 2654435761u) & mask;
    while (true) {
        unsigned prev = atomicCAS(&keys[s], 0xFFFFFFFFu, g);
        if (prev == 0xFFFFFFFFu || prev == g) { atomicMax(&vals[s], pos1); return; }
        s = (s + 1) & mask;
    }
}

__device__ inline int hfind(const unsigned* __restrict__ keys,
                            const unsigned* __restrict__ vals,
                            unsigned mask, unsigned g) {
    unsigned s = (g * 2654435761u) & mask;
    while (true) {
        unsigned k = keys[s];
        if (k == g) return (int)vals[s] - 1;
        if (k == 0xFFFFFFFFu) return -1;
        s = (s + 1) & mask;
    }
}

// ---------------- pre: hash init + permuted weight bf16 conversion -----------

__global__ void k_pre(unsigned* __restrict__ k0, unsigned* __restrict__ v0,
                      unsigned* __restrict__ k1, unsigned* __restrict__ v1,
                      const float* __restrict__ Qw0, const float* __restrict__ Qw1,
                      const float* __restrict__ Ww0, const float* __restrict__ Ww1,
                      unsigned short* __restrict__ Qw0b, unsigned short* __restrict__ Qw1b,
                      unsigned short* __restrict__ Ww0b, unsigned short* __restrict__ Ww1b) {
    int i = blockIdx.x * blockDim.x + threadIdx.x;
    int nt = gridDim.x * blockDim.x;
    for (int j = i; j < HS0; j += nt) { k0[j] = 0xFFFFFFFFu; v0[j] = 0u; }
    for (int j = i; j < HS1; j += nt) { k1[j] = 0xFFFFFFFFu; v1[j] = 0u; }
    for (int j = i; j < 128 * 128; j += nt) {
        int r = j >> 7, p = j & 127;
        int src = (r << 7) + kperm(p);
        Qw0b[j] = f2b(Qw0[src]); Qw1b[j] = f2b(Qw1[src]);
    }
    for (int j = i; j < 128 * 256; j += nt) {
        int r = j >> 8, p = j & 255;
        int src = (r << 8) + (p < 128 ? kperm(p) : p);
        Ww0b[j] = f2b(Ww0[src]); Ww1b[j] = f2b(Ww1[src]);
    }
}

// ---------------- fused layer: qagg (phase 1) + dense (phase 2) --------------
// block = 512 threads (8 waves) = 8 nodes (1 node per wave). VGPR-dieted for
// 5+ waves/SIMD. lA rows 8-15 zeroed (phase-2 MFMA M=16 with 8 valid rows).

__global__ __launch_bounds__(512, 5) void k_layer(
    const float* __restrict__ h, const unsigned short* __restrict__ newprevb,
    const unsigned* __restrict__ lk, const unsigned* __restrict__ lv, unsigned lmask,
    const int* __restrict__ nodeset, const int* __restrict__ nb,
    const float* __restrict__ nbw,
    const unsigned short* __restrict__ Qwb, const float* __restrict__ Qb,
    const unsigned short* __restrict__ Wwb, const float* __restrict__ Wb,
    float* __restrict__ outf, unsigned short* __restrict__ outb,
    const int* __restrict__ ins0, unsigned* __restrict__ ik0, unsigned* __restrict__ iv0,
    const int* __restrict__ ins1, unsigned* __restrict__ ik1, unsigned* __restrict__ iv1)
{
    __shared__ unsigned short lQ[128 * 128];   // 32 KB Qw bf16, XOR-swizzled
    __shared__ unsigned short lA[16 * 256];    // 8 KB: rows 0-7 data, 8-15 zero
    __shared__ float sred[8][16];
    const int tid = threadIdx.x;
    const int wid = tid >> 6, lane = tid & 63;
    const int row = lane & 15, kg = lane >> 4;
    const long mbase = (long)blockIdx.x * 8;

    // ---- map-building duty (layer0 only): 8(+8) inserts per block
    if (ik0) {
        if (tid < 8) {
            int i = (int)mbase + tid;
            hins(ik0, iv0, HS0 - 1, (unsigned)ins0[i], (unsigned)(i + 1));
        } else if (tid < 16 && blockIdx.x < 512) {
            int i = (int)mbase + tid - 8;
            hins(ik1, iv1, HS1 - 1, (unsigned)ins1[i], (unsigned)(i + 1));
        }
    }

    // ---- self-row gather: 128 threads (8 nodes x 16 threads x 32B)
    const int sr = tid >> 4, sq = tid & 15;
    const bool sact = tid < 128;
    bool sredir = false;
    float4 sv0, sv1;
    uint4 sb;
    if (sact) {
        int gs = nodeset[mbase + sr];
        int p = lk ? hfind(lk, lv, lmask, (unsigned)gs) : -1;
        if (p >= 0) {
            sredir = true;
            sb = *(const uint4*)(newprevb + (size_t)p * F + sq * 8);
        } else {
            const float4* s = (const float4*)(h + (size_t)gs * F);
            sv0 = s[sq]; sv1 = s[sq + 16];
        }
    }

    // ---- neighbor gather: 1 node per wave, full row per (row,kg) lane
    const long node = mbase + wid;
    int g = nb[node * 16 + row];
    int p = lk ? hfind(lk, lv, lmask, (unsigned)g) : -1;
    bf16x8 Ab[4];
    float4 av[8];
    if (p >= 0) {
        const bf16x8* s = (const bf16x8*)(newprevb + (size_t)p * F);
#pragma unroll
        for (int kk = 0; kk < 4; ++kk) Ab[kk] = s[kk * 4 + kg];
    } else {
        const float4* s4 = (const float4*)(h + (size_t)g * F);
#pragma unroll
        for (int c = 0; c < 8; ++c) av[c] = s4[c * 4 + kg];
    }

    // ---- stage Qw (kperm-ordered bf16) into swizzled LDS
    for (int c = tid; c < 2048; c += 512) {
        int j = c >> 4;
        uint4 v = ((const uint4*)Qwb)[c];
        *(uint4*)((char*)lQ + ((c << 4) ^ ((j & 7) << 4))) = v;
    }

    // ---- zero lA rows 8-15 (phase-2 dummy rows)
    ((uint2*)((char*)lA + 4096))[tid] = make_uint2(0u, 0u);

    // ---- neighbor weights
    float w[4];
#pragma unroll
    for (int r = 0; r < 4; ++r) w[r] = nbw[node * 16 + kg * 4 + r];

    // ---- pack neighbor row fp32 -> bf16
    if (p < 0) {
#pragma unroll
        for (int kk = 0; kk < 4; ++kk) Ab[kk] = pack8(av[2 * kk], av[2 * kk + 1]);
    }

    // ---- write self rows to lA (bf16, kperm-ordered, swizzled)
    if (sact) {
        int swz = (sr & 7) << 4;
        if (sredir) {
            int b0 = sr * 512 + sq * 16;
            *(uint4*)((char*)lA + (b0 ^ swz)) = sb;
        } else {
            int pp = ((sq >> 3) << 5) + ((sq & 3) << 3) + ((sq & 4) ? 4 : 0);
            int b1 = sr * 512 + pp * 2;
            *(uint2*)((char*)lA + (b1 ^ swz)) = pack4(sv0);
            *(uint2*)((char*)lA + ((b1 + 128) ^ swz)) = pack4(sv1);
        }
    }
    __syncthreads();

    // ---- phase 1: qagg MFMA, two 64-col halves (acc = 16 VGPR)
    float ws = w[0] + w[1] + w[2] + w[3];
    ws += __shfl_xor(ws, 16);
    ws += __shfl_xor(ws, 32);
    float inv = (ws == 0.f) ? 1.f : 1.f / ws;

#pragma unroll 1
    for (int half = 0; half < 2; ++half) {
        f32x4 acc[4];
#pragma unroll
        for (int jt = 0; jt < 4; ++jt) acc[jt] = (f32x4){0.f, 0.f, 0.f, 0.f};

#pragma unroll
        for (int kk = 0; kk < 4; ++kk) {
            bf16x8 Bf[4];
#pragma unroll
            for (int jt = 0; jt < 4; ++jt) {
                int j = (half * 4 + jt) * 16 + row;
                int byte = ((j << 8) + (kk << 6) + (kg << 4)) ^ ((j & 7) << 4);
                Bf[jt] = *(bf16x8*)((char*)lQ + byte);
            }
#pragma unroll
            for (int jt = 0; jt < 4; ++jt)
                acc[jt] = __builtin_amdgcn_mfma_f32_16x16x32_bf16(Ab[kk], Bf[jt], acc[jt], 0, 0, 0);
        }

#pragma unroll
        for (int jt = 0; jt < 4; ++jt) {
            int jtg = half * 4 + jt;
            float qb = Qb[jtg * 16 + row];
            float t = 0.f;
#pragma unroll
            for (int r = 0; r < 4; ++r) {
                float v = acc[jt][r] + qb;
                v = v > 0.f ? v : 0.01f * v;
                t = fmaf(w[r], v, t);
            }
            t += __shfl_xor(t, 16);
            t += __shfl_xor(t, 32);
            if (lane < 16) {
                int byte = (wid * 512 + 256 + jtg * 32 + lane * 2) ^ ((wid & 7) << 4);
                *(unsigned short*)((char*)lA + byte) = f2b(t * inv);
            }
        }
    }
    __syncthreads();

    // ---- phase 2: dense 8x256 @ Ww^T (M=16 MFMA, rows 8-15 zero)
    const int j = wid * 16 + row;
    f32x4 dacc = (f32x4){0.f, 0.f, 0.f, 0.f};
#pragma unroll
    for (int kk = 0; kk < 8; ++kk) {
        bf16x8 a = *(bf16x8*)((char*)lA + ((row * 512 + kk * 64 + kg * 16) ^ ((row & 7) << 4)));
        bf16x8 b = ((const bf16x8*)(Wwb + (size_t)j * 256))[kk * 4 + kg];
        dacc = __builtin_amdgcn_mfma_f32_16x16x32_bf16(a, b, dacc, 0, 0, 0);
    }

    float wb = Wb[j];
    float ss[4];
#pragma unroll
    for (int r = 0; r < 4; ++r) {
        float v = dacc[r] + wb;
        v = v > 0.f ? v : 0.01f * v;
        dacc[r] = v;
        ss[r] = v * v;
    }
#pragma unroll
    for (int r = 0; r < 4; ++r) {
        ss[r] += __shfl_xor(ss[r], 1);
        ss[r] += __shfl_xor(ss[r], 2);
        ss[r] += __shfl_xor(ss[r], 4);
        ss[r] += __shfl_xor(ss[r], 8);
    }
    if (row == 0) {
#pragma unroll
        for (int r = 0; r < 4; ++r) sred[wid][kg * 4 + r] = ss[r];
    }
    __syncthreads();
    if (kg < 2) {   // output rows kg*4+r in 0..7 only
        float invn[4];
#pragma unroll
        for (int r = 0; r < 4; ++r) {
            float s = 0.f;
#pragma unroll
            for (int w8 = 0; w8 < 8; ++w8) s += sred[w8][kg * 4 + r];
            float n = sqrtf(s);
            invn[r] = (n == 0.f) ? 1.f : 1.f / n;
        }
        if (outf) {
#pragma unroll
            for (int r = 0; r < 4; ++r)
                outf[(size_t)(mbase + kg * 4 + r) * F + j] = dacc[r] * invn[r];
        } else {
            int pj = ((j >> 5) << 5) + (((j & 15) >> 2) << 3) + ((j & 16) ? 4 : 0) + (j & 3);
#pragma unroll
            for (int r = 0; r < 4; ++r)
                outb[(size_t)(mbase + kg * 4 + r) * F + pj] = f2b(dacc[r] * invn[r]);
        }
    }
}

// ---------------- duplicate-row fixup on d_out -------------------------------

__global__ void k_fix(const unsigned* __restrict__ k1, const unsigned* __restrict__ v1,
                      const int* __restrict__ ns1, float* __restrict__ out, int n) {
    int i = blockIdx.x * blockDim.x + threadIdx.x;
    if (i < n) {
        int p = hfind(k1, v1, HS1 - 1, (unsigned)ns1[i]);
        if (p != i) {
            float4* o = (float4*)out;
#pragma unroll
            for (int c = 0; c < 32; ++c) o[(size_t)i * 32 + c] = o[(size_t)p * 32 + c];
        }
    }
}

// ---------------- launcher ---------------------------------------------------

extern "C" void kernel_launch(void* const* d_in, const int* in_sizes, int n_in,
                              void* d_out, int out_size, void* d_ws, size_t ws_size,
                              hipStream_t stream) {
    const float* h    = (const float*)d_in[0];
    const float* Qw0  = (const float*)d_in[1];
    const float* Qb0  = (const float*)d_in[2];
    const float* Ww0  = (const float*)d_in[3];
    const float* Wb0  = (const float*)d_in[4];
    const float* Qw1  = (const float*)d_in[5];
    const float* Qb1  = (const float*)d_in[6];
    const float* Ww1  = (const float*)d_in[7];
    const float* Wb1  = (const float*)d_in[8];
    const int*   ns0  = (const int*)d_in[9];
    const int*   nb0  = (const int*)d_in[10];
    const float* nbw0 = (const float*)d_in[11];
    const int*   ns1  = (const int*)d_in[12];
    const int*   nb1  = (const int*)d_in[13];
    const float* nbw1 = (const float*)d_in[14];

    // ws: k0|v0|k1|v1 hash | new0b bf16 | Qw0b | Qw1b | Ww0b | Ww1b
    unsigned* hk0 = (unsigned*)d_ws;
    unsigned* hv0 = hk0 + HS0;
    unsigned* hk1 = hv0 + HS0;
    unsigned* hv1 = hk1 + HS1;
    unsigned short* new0b = (unsigned short*)(hv1 + HS1);
    unsigned short* Qw0b = new0b + (size_t)N0 * F;
    unsigned short* Qw1b = Qw0b + 128 * 128;
    unsigned short* Ww0b = Qw1b + 128 * 128;
    unsigned short* Ww1b = Ww0b + 128 * 256;

    k_pre<<<128, 256, 0, stream>>>(hk0, hv0, hk1, hv1,
                                   Qw0, Qw1, Ww0, Ww1, Qw0b, Qw1b, Ww0b, Ww1b);

    // layer 0 (reads original h; writes new0 bf16 kperm-ordered; builds maps)
    k_layer<<<N0 / 8, 512, 0, stream>>>(h, nullptr, nullptr, nullptr, 0u,
                                        ns0, nb0, nbw0, Qw0b, Qb0, Ww0b, Wb0,
                                        nullptr, new0b,
                                        ns0, hk0, hv0, ns1, hk1, hv1);

    // layer 1 (h with nodeset0 rows redirected to new0b; writes d_out f32)
    k_layer<<<N1 / 8, 512, 0, stream>>>(h, new0b, hk0, hv0, HS0 - 1,
                                        ns1, nb1, nbw1, Qw1b, Qb1, Ww1b, Wb1,
                                        (float*)d_out, nullptr,
                                        nullptr, nullptr, nullptr, nullptr, nullptr, nullptr);

    k_fix<<<(N1 + 255) / 256, 256, 0, stream>>>(hk1, hv1, ns1, (float*)d_out, N1);
}

// Round 10
// 80.213 us; speedup vs baseline: 1.0953x; 1.0953x over previous
//
#include <hip/hip_runtime.h>
#include <hip/hip_bf16.h>
#include <math.h>

#define NN 1000000
#define F 128
#define N0 16384
#define N1 4096
#define HS0 65536
#define HS1 16384

typedef __attribute__((ext_vector_type(8))) short bf16x8;
typedef __attribute__((ext_vector_type(4))) float f32x4;

__device__ inline unsigned short f2b(float f) {
    union { float f; unsigned u; } v; v.f = f;
    unsigned r = v.u + 0x7FFFu + ((v.u >> 16) & 1u);
    return (unsigned short)(r >> 16);
}

__device__ inline bf16x8 pack8(float4 a, float4 b) {
    union { __hip_bfloat162 h2[4]; bf16x8 v; } u;
    u.h2[0] = __float22bfloat162_rn(make_float2(a.x, a.y));
    u.h2[1] = __float22bfloat162_rn(make_float2(a.z, a.w));
    u.h2[2] = __float22bfloat162_rn(make_float2(b.x, b.y));
    u.h2[3] = __float22bfloat162_rn(make_float2(b.z, b.w));
    return u.v;
}

__device__ inline uint2 pack4(float4 a) {
    union { __hip_bfloat162 h2[2]; uint2 v; } u;
    u.h2[0] = __float22bfloat162_rn(make_float2(a.x, a.y));
    u.h2[1] = __float22bfloat162_rn(make_float2(a.z, a.w));
    return u.v;
}

// k-permutation: storage position p -> source element pi(p), p in [0,128).
__device__ inline int kperm(int p) {
    int kk = p >> 5, kg = (p >> 3) & 3, e = p & 7;
    return kk * 32 + kg * 4 + (e < 4 ? e : e + 12);
}

// ---------------- open-addressing hash (last-occurrence-wins) ----------------

__device__ inline void hins(unsigned* __restrict__ keys, unsigned* __restrict__ vals,
                            unsigned mask, unsigned g, unsigned pos1) {
    unsigned s = (g * 2654435761u) & mask;
    while (true) {
        unsigned prev = atomicCAS(&keys[s], 0xFFFFFFFFu, g);
        if (prev == 0xFFFFFFFFu || prev == g) { atomicMax(&vals[s], pos1); return; }
        s = (s + 1) & mask;
    }
}

__device__ inline int hfind(const unsigned* __restrict__ keys,
                            const unsigned* __restrict__ vals,
                            unsigned mask, unsigned g) {
    unsigned s = (g * 2654435761u) & mask;
    while (true) {
        unsigned k = keys[s];
        if (k == g) return (int)vals[s] - 1;
        if (k == 0xFFFFFFFFu) return -1;
        s = (s + 1) & mask;
    }
}

// ---------------- pre: hash init + permuted weight bf16 conversion -----------

__global__ void k_pre(unsigned* __restrict__ k0, unsigned* __restrict__ v0,
                      unsigned* __restrict__ k1, unsigned* __restrict__ v1,
                      const float* __restrict__ Qw0, const float* __restrict__ Qw1,
                      const float* __restrict__ Ww0, const float* __restrict__ Ww1,
                      unsigned short* __restrict__ Qw0b, unsigned short* __restrict__ Qw1b,
                      unsigned short* __restrict__ Ww0b, unsigned short* __restrict__ Ww1b) {
    int i = blockIdx.x * blockDim.x + threadIdx.x;
    int nt = gridDim.x * blockDim.x;
    for (int j = i; j < HS0; j += nt) { k0[j] = 0xFFFFFFFFu; v0[j] = 0u; }
    for (int j = i; j < HS1; j += nt) { k1[j] = 0xFFFFFFFFu; v1[j] = 0u; }
    for (int j = i; j < 128 * 128; j += nt) {
        int r = j >> 7, p = j & 127;
        int src = (r << 7) + kperm(p);
        Qw0b[j] = f2b(Qw0[src]); Qw1b[j] = f2b(Qw1[src]);
    }
    for (int j = i; j < 128 * 256; j += nt) {
        int r = j >> 8, p = j & 255;
        int src = (r << 8) + (p < 128 ? kperm(p) : p);
        Ww0b[j] = f2b(Ww0[src]); Ww1b[j] = f2b(Ww1[src]);
    }
}

// ---------------- fused layer: qagg (phase 1) + dense (phase 2) --------------
// NW waves of 64, 2 nodes per wave, NODES = 2*NW per block.
// NW=8: 512 thr, 16 nodes (layer 0). NW=4: 256 thr, 8 nodes, 4 blocks/CU (layer 1).

template<int NW>
__global__ __launch_bounds__(NW * 64, 4) void k_layer(
    const float* __restrict__ h, const unsigned short* __restrict__ newprevb,
    const unsigned* __restrict__ lk, const unsigned* __restrict__ lv, unsigned lmask,
    const int* __restrict__ nodeset, const int* __restrict__ nb,
    const float* __restrict__ nbw,
    const unsigned short* __restrict__ Qwb, const float* __restrict__ Qb,
    const unsigned short* __restrict__ Wwb, const float* __restrict__ Wb,
    float* __restrict__ outf, unsigned short* __restrict__ outb,
    const int* __restrict__ ins0, unsigned* __restrict__ ik0, unsigned* __restrict__ iv0,
    const int* __restrict__ ins1, unsigned* __restrict__ ik1, unsigned* __restrict__ iv1)
{
    constexpr int NODES = NW * 2;
    constexpr int NT = NW * 64;
    constexpr int JL = 8 / NW;          // col-groups per wave in phase 2
    __shared__ unsigned short lQ[128 * 128];      // 32 KB Qw bf16, XOR-swizzled
    __shared__ unsigned short lA[NODES * 256];    // [node][self 0..127 | agg 128..255]
    __shared__ float sred[NW][16];
    const int tid = threadIdx.x;
    const int wid = tid >> 6, lane = tid & 63;
    const int row = lane & 15, kg = lane >> 4;
    const long mbase = (long)blockIdx.x * NODES;

    // ---- map-building duty (layer0 only)
    if (ik0) {
        int base = blockIdx.x * NODES;
        if (tid < NODES) {
            int i = base + tid;
            if (i < N0) hins(ik0, iv0, HS0 - 1, (unsigned)ins0[i], (unsigned)(i + 1));
        } else if (tid < 2 * NODES) {
            int i = base + tid - NODES;
            if (i < N1) hins(ik1, iv1, HS1 - 1, (unsigned)ins1[i], (unsigned)(i + 1));
        }
    }

    // ---- self-row gather: NODES*16 threads, 32B fp32 (16B bf16 redirect) each
    const int sr = tid >> 4, sq = tid & 15;
    const bool sact = tid < NODES * 16;
    bool sredir = false;
    float4 sv0, sv1;
    uint4 sb;
    if (sact) {
        int gs = nodeset[mbase + sr];
        int p = lk ? hfind(lk, lv, lmask, (unsigned)gs) : -1;
        if (p >= 0) {
            sredir = true;
            sb = *(const uint4*)(newprevb + (size_t)p * F + sq * 8);
        } else {
            const float4* s = (const float4*)(h + (size_t)gs * F);
            sv0 = s[sq]; sv1 = s[sq + 16];
        }
    }

    // ---- neighbor gathers: 2 nodes per wave, contiguous 16B per lane/line
    const long nodebase = mbase + wid * 2;
    int g0 = nb[nodebase * 16 + row];
    int g1 = nb[(nodebase + 1) * 16 + row];
    int p0 = lk ? hfind(lk, lv, lmask, (unsigned)g0) : -1;
    int p1 = lk ? hfind(lk, lv, lmask, (unsigned)g1) : -1;
    bf16x8 Ab[2][4];
    float4 av[2][8];
    if (p0 >= 0) {
        const bf16x8* s = (const bf16x8*)(newprevb + (size_t)p0 * F);
#pragma unroll
        for (int kk = 0; kk < 4; ++kk) Ab[0][kk] = s[kk * 4 + kg];
    } else {
        const float4* s4 = (const float4*)(h + (size_t)g0 * F);
#pragma unroll
        for (int c = 0; c < 8; ++c) av[0][c] = s4[c * 4 + kg];
    }
    if (p1 >= 0) {
        const bf16x8* s = (const bf16x8*)(newprevb + (size_t)p1 * F);
#pragma unroll
        for (int kk = 0; kk < 4; ++kk) Ab[1][kk] = s[kk * 4 + kg];
    } else {
        const float4* s4 = (const float4*)(h + (size_t)g1 * F);
#pragma unroll
        for (int c = 0; c < 8; ++c) av[1][c] = s4[c * 4 + kg];
    }

    // ---- stage Qw (kperm-ordered bf16) into swizzled LDS
    for (int c = tid; c < 2048; c += NT) {
        int j = c >> 4;
        uint4 v = ((const uint4*)Qwb)[c];
        *(uint4*)((char*)lQ + ((c << 4) ^ ((j & 7) << 4))) = v;
    }

    // ---- neighbor weights
    float w[2][4];
#pragma unroll
    for (int nn = 0; nn < 2; ++nn)
#pragma unroll
        for (int r = 0; r < 4; ++r) w[nn][r] = nbw[(nodebase + nn) * 16 + kg * 4 + r];

    // ---- pack neighbor rows fp32 -> bf16 (kperm slot order)
    if (p0 < 0) {
#pragma unroll
        for (int kk = 0; kk < 4; ++kk) Ab[0][kk] = pack8(av[0][2 * kk], av[0][2 * kk + 1]);
    }
    if (p1 < 0) {
#pragma unroll
        for (int kk = 0; kk < 4; ++kk) Ab[1][kk] = pack8(av[1][2 * kk], av[1][2 * kk + 1]);
    }

    // ---- write self rows to lA (bf16, kperm-ordered, swizzled)
    if (sact) {
        int swz = (sr & 7) << 4;
        if (sredir) {
            int b0 = sr * 512 + sq * 16;
            *(uint4*)((char*)lA + (b0 ^ swz)) = sb;
        } else {
            int pp = ((sq >> 3) << 5) + ((sq & 3) << 3) + ((sq & 4) ? 4 : 0);
            int b1 = sr * 512 + pp * 2;
            *(uint2*)((char*)lA + (b1 ^ swz)) = pack4(sv0);
            *(uint2*)((char*)lA + ((b1 + 128) ^ swz)) = pack4(sv1);
        }
    }
    __syncthreads();

    // ---- phase 1: qagg MFMA, two 64-col halves (acc = 32 VGPR)
    float inv[2];
#pragma unroll
    for (int nn = 0; nn < 2; ++nn) {
        float ws = w[nn][0] + w[nn][1] + w[nn][2] + w[nn][3];
        ws += __shfl_xor(ws, 16);
        ws += __shfl_xor(ws, 32);
        inv[nn] = (ws == 0.f) ? 1.f : 1.f / ws;
    }

#pragma unroll 1
    for (int half = 0; half < 2; ++half) {
        f32x4 acc[2][4];
#pragma unroll
        for (int nn = 0; nn < 2; ++nn)
#pragma unroll
            for (int jt = 0; jt < 4; ++jt)
                acc[nn][jt] = (f32x4){0.f, 0.f, 0.f, 0.f};

#pragma unroll
        for (int kk = 0; kk < 4; ++kk) {
            bf16x8 Bf[4];
#pragma unroll
            for (int jt = 0; jt < 4; ++jt) {
                int j = (half * 4 + jt) * 16 + row;
                int byte = ((j << 8) + (kk << 6) + (kg << 4)) ^ ((j & 7) << 4);
                Bf[jt] = *(bf16x8*)((char*)lQ + byte);
            }
#pragma unroll
            for (int jt = 0; jt < 4; ++jt) {
                acc[0][jt] = __builtin_amdgcn_mfma_f32_16x16x32_bf16(Ab[0][kk], Bf[jt], acc[0][jt], 0, 0, 0);
                acc[1][jt] = __builtin_amdgcn_mfma_f32_16x16x32_bf16(Ab[1][kk], Bf[jt], acc[1][jt], 0, 0, 0);
            }
        }

#pragma unroll
        for (int nn = 0; nn < 2; ++nn) {
            int nl = wid * 2 + nn;
#pragma unroll
            for (int jt = 0; jt < 4; ++jt) {
                int jtg = half * 4 + jt;
                float qb = Qb[jtg * 16 + row];
                float t = 0.f;
#pragma unroll
                for (int r = 0; r < 4; ++r) {
                    float v = acc[nn][jt][r] + qb;
                    v = v > 0.f ? v : 0.01f * v;
                    t = fmaf(w[nn][r], v, t);
                }
                t += __shfl_xor(t, 16);
                t += __shfl_xor(t, 32);
                if (lane < 16) {
                    int byte = (nl * 512 + 256 + jtg * 32 + lane * 2) ^ ((nl & 7) << 4);
                    *(unsigned short*)((char*)lA + byte) = f2b(t * inv[nn]);
                }
            }
        }
    }
    __syncthreads();

    // ---- phase 2: dense NODESx256 @ Ww^T (M=16 MFMA; NW=4: A rows 8-15 = 0)
    f32x4 dacc[JL];
    float wb[JL];
#pragma unroll
    for (int jl = 0; jl < JL; ++jl) {
        dacc[jl] = (f32x4){0.f, 0.f, 0.f, 0.f};
        wb[jl] = Wb[(wid + jl * NW) * 16 + row];
    }
#pragma unroll
    for (int kk = 0; kk < 8; ++kk) {
        bf16x8 a = {0, 0, 0, 0, 0, 0, 0, 0};
        if (NW == 8 || row < 8)
            a = *(bf16x8*)((char*)lA + ((row * 512 + kk * 64 + kg * 16) ^ ((row & 7) << 4)));
#pragma unroll
        for (int jl = 0; jl < JL; ++jl) {
            int j = (wid + jl * NW) * 16 + row;
            bf16x8 b = ((const bf16x8*)(Wwb + (size_t)j * 256))[kk * 4 + kg];
            dacc[jl] = __builtin_amdgcn_mfma_f32_16x16x32_bf16(a, b, dacc[jl], 0, 0, 0);
        }
    }

    float ss[4] = {0.f, 0.f, 0.f, 0.f};
#pragma unroll
    for (int jl = 0; jl < JL; ++jl) {
#pragma unroll
        for (int r = 0; r < 4; ++r) {
            float v = dacc[jl][r] + wb[jl];
            v = v > 0.f ? v : 0.01f * v;
            dacc[jl][r] = v;
            ss[r] = fmaf(v, v, ss[r]);
        }
    }
#pragma unroll
    for (int r = 0; r < 4; ++r) {
        ss[r] += __shfl_xor(ss[r], 1);
        ss[r] += __shfl_xor(ss[r], 2);
        ss[r] += __shfl_xor(ss[r], 4);
        ss[r] += __shfl_xor(ss[r], 8);
    }
    if (row == 0) {
#pragma unroll
        for (int r = 0; r < 4; ++r) sred[wid][kg * 4 + r] = ss[r];
    }
    __syncthreads();
    if (kg * 4 < NODES) {
        float invn[4];
#pragma unroll
        for (int r = 0; r < 4; ++r) {
            float s = 0.f;
#pragma unroll
            for (int w8 = 0; w8 < NW; ++w8) s += sred[w8][kg * 4 + r];
            float n = sqrtf(s);
            invn[r] = (n == 0.f) ? 1.f : 1.f / n;
        }
#pragma unroll
        for (int jl = 0; jl < JL; ++jl) {
            int j = (wid + jl * NW) * 16 + row;
            if (outf) {
#pragma unroll
                for (int r = 0; r < 4; ++r)
                    outf[(size_t)(mbase + kg * 4 + r) * F + j] = dacc[jl][r] * invn[r];
            } else {
                int pj = ((j >> 5) << 5) + (((j & 15) >> 2) << 3) + ((j & 16) ? 4 : 0) + (j & 3);
#pragma unroll
                for (int r = 0; r < 4; ++r)
                    outb[(size_t)(mbase + kg * 4 + r) * F + pj] = f2b(dacc[jl][r] * invn[r]);
            }
        }
    }
}

// ---------------- duplicate-row fixup on d_out -------------------------------

__global__ void k_fix(const unsigned* __restrict__ k1, const unsigned* __restrict__ v1,
                      const int* __restrict__ ns1, float* __restrict__ out, int n) {
    int i = blockIdx.x * blockDim.x + threadIdx.x;
    if (i < n) {
        int p = hfind(k1, v1, HS1 - 1, (unsigned)ns1[i]);
        if (p != i) {
            float4* o = (float4*)out;
#pragma unroll
            for (int c = 0; c < 32; ++c) o[(size_t)i * 32 + c] = o[(size_t)p * 32 + c];
        }
    }
}

// ---------------- launcher ---------------------------------------------------

extern "C" void kernel_launch(void* const* d_in, const int* in_sizes, int n_in,
                              void* d_out, int out_size, void* d_ws, size_t ws_size,
                              hipStream_t stream) {
    const float* h    = (const float*)d_in[0];
    const float* Qw0  = (const float*)d_in[1];
    const float* Qb0  = (const float*)d_in[2];
    const float* Ww0  = (const float*)d_in[3];
    const float* Wb0  = (const float*)d_in[4];
    const float* Qw1  = (const float*)d_in[5];
    const float* Qb1  = (const float*)d_in[6];
    const float* Ww1  = (const float*)d_in[7];
    const float* Wb1  = (const float*)d_in[8];
    const int*   ns0  = (const int*)d_in[9];
    const int*   nb0  = (const int*)d_in[10];
    const float* nbw0 = (const float*)d_in[11];
    const int*   ns1  = (const int*)d_in[12];
    const int*   nb1  = (const int*)d_in[13];
    const float* nbw1 = (const float*)d_in[14];

    // ws: k0|v0|k1|v1 hash | new0b bf16 | Qw0b | Qw1b | Ww0b | Ww1b
    unsigned* hk0 = (unsigned*)d_ws;
    unsigned* hv0 = hk0 + HS0;
    unsigned* hk1 = hv0 + HS0;
    unsigned* hv1 = hk1 + HS1;
    unsigned short* new0b = (unsigned short*)(hv1 + HS1);
    unsigned short* Qw0b = new0b + (size_t)N0 * F;
    unsigned short* Qw1b = Qw0b + 128 * 128;
    unsigned short* Ww0b = Qw1b + 128 * 128;
    unsigned short* Ww1b = Ww0b + 128 * 256;

    k_pre<<<128, 256, 0, stream>>>(hk0, hv0, hk1, hv1,
                                   Qw0, Qw1, Ww0, Ww1, Qw0b, Qw1b, Ww0b, Ww1b);

    // layer 0 (reads original h; writes new0 bf16 kperm-ordered; builds maps)
    k_layer<8><<<N0 / 16, 512, 0, stream>>>(h, nullptr, nullptr, nullptr, 0u,
                                            ns0, nb0, nbw0, Qw0b, Qb0, Ww0b, Wb0,
                                            nullptr, new0b,
                                            ns0, hk0, hv0, ns1, hk1, hv1);

    // layer 1 (h with nodeset0 rows redirected to new0b; writes d_out f32)
    k_layer<4><<<N1 / 8, 256, 0, stream>>>(h, new0b, hk0, hv0, HS0 - 1,
                                           ns1, nb1, nbw1, Qw1b, Qb1, Ww1b, Wb1,
                                           (float*)d_out, nullptr,
                                           nullptr, nullptr, nullptr, nullptr, nullptr, nullptr);

    k_fix<<<(N1 + 255) / 256, 256, 0, stream>>>(hk1, hv1, ns1, (float*)d_out, N1);
}

// Round 11
// 79.166 us; speedup vs baseline: 1.1098x; 1.0132x over previous
//
#include <hip/hip_runtime.h>
#include <hip/hip_bf16.h>
#include <math.h>

#define NN 1000000
#define F 128
#define N0 16384
#define N1 4096

typedef __attribute__((ext_vector_type(8))) short bf16x8;
typedef __attribute__((ext_vector_type(4))) float f32x4;

__device__ inline unsigned short f2b(float f) {
    union { float f; unsigned u; } v; v.f = f;
    unsigned r = v.u + 0x7FFFu + ((v.u >> 16) & 1u);
    return (unsigned short)(r >> 16);
}

__device__ inline bf16x8 pack8(float4 a, float4 b) {
    union { __hip_bfloat162 h2[4]; bf16x8 v; } u;
    u.h2[0] = __float22bfloat162_rn(make_float2(a.x, a.y));
    u.h2[1] = __float22bfloat162_rn(make_float2(a.z, a.w));
    u.h2[2] = __float22bfloat162_rn(make_float2(b.x, b.y));
    u.h2[3] = __float22bfloat162_rn(make_float2(b.z, b.w));
    return u.v;
}

// ---------------- prep: maps (last-wins) + weight bf16 conversion ------------
// maps pre-initialized to -1 via hipMemsetAsync(0xFF)

__global__ void k_prep(const int* __restrict__ ns0, const int* __restrict__ ns1,
                       int* __restrict__ map0, int* __restrict__ map1,
                       const float* __restrict__ Qw0, const float* __restrict__ Qw1,
                       const float* __restrict__ Ww0, const float* __restrict__ Ww1,
                       unsigned short* __restrict__ Qw0b, unsigned short* __restrict__ Qw1b,
                       unsigned short* __restrict__ Ww0b, unsigned short* __restrict__ Ww1b) {
    int i = blockIdx.x * blockDim.x + threadIdx.x;
    int nt = gridDim.x * blockDim.x;
    if (i < N0) atomicMax(&map0[ns0[i]], i);
    if (i < N1) atomicMax(&map1[ns1[i]], i);
    for (int j = i; j < 128 * 128; j += nt) { Qw0b[j] = f2b(Qw0[j]); Qw1b[j] = f2b(Qw1[j]); }
    for (int j = i; j < 128 * 256; j += nt) { Ww0b[j] = f2b(Ww0[j]); Ww1b[j] = f2b(Ww1[j]); }
}

// ---------------- fused layer: qagg (phase 1) + dense (phase 2) --------------
// block = 512 threads (8 waves) = 16 nodes. VGPR-capped for 2 blocks/CU.

__global__ __launch_bounds__(512, 4) void k_layer(
    const float* __restrict__ h, const unsigned short* __restrict__ newprevb,
    const int* __restrict__ mapprev,
    const int* __restrict__ nodeset, const int* __restrict__ nb,
    const float* __restrict__ nbw,
    const unsigned short* __restrict__ Qwb, const float* __restrict__ Qb,
    const unsigned short* __restrict__ Wwb, const float* __restrict__ Wb,
    float* __restrict__ outf, unsigned short* __restrict__ outb)
{
    __shared__ unsigned short lQ[128 * 128];   // 32 KB Qw bf16, XOR-swizzled
    __shared__ unsigned short lA[16 * 256];    // 8 KB: [node][self 0..127 | agg 128..255]
    __shared__ float sred[8][16];
    const int tid = threadIdx.x;
    const int wid = tid >> 6, lane = tid & 63;
    const int row = lane & 15, kg = lane >> 4;
    const long mbase = (long)blockIdx.x * 16;

    // ---- issue self-row gather (threads 0..127; 8 lanes per node row)
    float4 sv[4];
    uint4 sb[2];
    bool sredir = false;
    const int sq = tid & 7;
    if (tid < 128) {
        int sr = tid >> 3;
        int gs = nodeset[mbase + sr];
        int p = mapprev ? mapprev[gs] : -1;
        if (p >= 0) {
            sredir = true;
            const uint4* s = (const uint4*)(newprevb + (size_t)p * F + sq * 16);
            sb[0] = s[0]; sb[1] = s[1];
        } else {
            const float4* s = (const float4*)(h + (size_t)gs * F + sq * 16);
            sv[0] = s[0]; sv[1] = s[1]; sv[2] = s[2]; sv[3] = s[3];
        }
    }

    // ---- neighbor weights (issue early, tiny)
    const long nodebase = mbase + wid * 2;
    float w[2][4];
#pragma unroll
    for (int nn = 0; nn < 2; ++nn)
#pragma unroll
        for (int r = 0; r < 4; ++r) w[nn][r] = nbw[(nodebase + nn) * 16 + kg * 4 + r];

    // ---- issue neighbor gathers (2 nodes per wave), pack to bf16 promptly
    bf16x8 Ab[2][4];
    {
        float4 av[2][8];
        bool redir[2];
#pragma unroll
        for (int nn = 0; nn < 2; ++nn) {
            long node = nodebase + nn;
            int g = nb[node * 16 + row];
            int p = mapprev ? mapprev[g] : -1;
            redir[nn] = (p >= 0);
            if (p >= 0) {
                const bf16x8* s = (const bf16x8*)(newprevb + (size_t)p * F);
#pragma unroll
                for (int kk = 0; kk < 4; ++kk) Ab[nn][kk] = s[kk * 4 + kg];
            } else {
                const float4* s4 = (const float4*)(h + (size_t)g * F);
#pragma unroll
                for (int kk = 0; kk < 4; ++kk) {
                    av[nn][kk * 2]     = s4[kk * 8 + kg * 2];
                    av[nn][kk * 2 + 1] = s4[kk * 8 + kg * 2 + 1];
                }
            }
        }
#pragma unroll
        for (int nn = 0; nn < 2; ++nn)
            if (!redir[nn]) {
#pragma unroll
                for (int kk = 0; kk < 4; ++kk)
                    Ab[nn][kk] = pack8(av[nn][kk * 2], av[nn][kk * 2 + 1]);
            }
    }

    // ---- stage Qw into swizzled LDS
    for (int c = tid; c < 2048; c += 512) {
        int j = c >> 4;
        uint4 v = ((const uint4*)Qwb)[c];
        *(uint4*)((char*)lQ + ((c << 4) ^ ((j & 7) << 4))) = v;
    }

    // ---- write self rows to lA (bf16, swizzled)
    if (tid < 128) {
        int sr = tid >> 3;
        int b0 = sr * 512 + sq * 32;
        int swz = (sr & 7) << 4;
        if (sredir) {
            *(uint4*)((char*)lA + (b0 ^ swz)) = sb[0];
            *(uint4*)((char*)lA + ((b0 + 16) ^ swz)) = sb[1];
        } else {
            *(bf16x8*)((char*)lA + (b0 ^ swz)) = pack8(sv[0], sv[1]);
            *(bf16x8*)((char*)lA + ((b0 + 16) ^ swz)) = pack8(sv[2], sv[3]);
        }
    }
    __syncthreads();

    // ---- phase 1: qagg MFMA, split into two 64-col halves (acc = 32 VGPR)
    float inv[2];
#pragma unroll
    for (int nn = 0; nn < 2; ++nn) {
        float ws = w[nn][0] + w[nn][1] + w[nn][2] + w[nn][3];
        ws += __shfl_xor(ws, 16);
        ws += __shfl_xor(ws, 32);
        inv[nn] = (ws == 0.f) ? 1.f : 1.f / ws;
    }

#pragma unroll 1
    for (int half = 0; half < 2; ++half) {
        f32x4 acc[2][4];
#pragma unroll
        for (int nn = 0; nn < 2; ++nn)
#pragma unroll
            for (int jt = 0; jt < 4; ++jt)
                acc[nn][jt] = (f32x4){0.f, 0.f, 0.f, 0.f};

#pragma unroll
        for (int kk = 0; kk < 4; ++kk) {
            bf16x8 Bf[4];
#pragma unroll
            for (int jt = 0; jt < 4; ++jt) {
                int j = (half * 4 + jt) * 16 + row;
                int byte = ((j << 8) + (kk << 6) + (kg << 4)) ^ ((j & 7) << 4);
                Bf[jt] = *(bf16x8*)((char*)lQ + byte);
            }
#pragma unroll
            for (int jt = 0; jt < 4; ++jt) {
                acc[0][jt] = __builtin_amdgcn_mfma_f32_16x16x32_bf16(Ab[0][kk], Bf[jt], acc[0][jt], 0, 0, 0);
                acc[1][jt] = __builtin_amdgcn_mfma_f32_16x16x32_bf16(Ab[1][kk], Bf[jt], acc[1][jt], 0, 0, 0);
            }
        }

        // epilogue for this half: bias + leaky + weighted reduce -> lA agg (bf16)
#pragma unroll
        for (int nn = 0; nn < 2; ++nn) {
            int nl = wid * 2 + nn;
#pragma unroll
            for (int jt = 0; jt < 4; ++jt) {
                int jtg = half * 4 + jt;
                float qb = Qb[jtg * 16 + row];
                float t = 0.f;
#pragma unroll
                for (int r = 0; r < 4; ++r) {
                    float v = acc[nn][jt][r] + qb;
                    v = v > 0.f ? v : 0.01f * v;
                    t = fmaf(w[nn][r], v, t);
                }
                t += __shfl_xor(t, 16);
                t += __shfl_xor(t, 32);
                if (lane < 16) {
                    int byte = (nl * 512 + 256 + jtg * 32 + lane * 2) ^ ((nl & 7) << 4);
                    *(unsigned short*)((char*)lA + byte) = f2b(t * inv[nn]);
                }
            }
        }
    }
    __syncthreads();

    // ---- phase 2: dense 16x256 @ Ww^T, this wave = 16 output cols
    const int j = wid * 16 + row;
    f32x4 dacc = (f32x4){0.f, 0.f, 0.f, 0.f};
#pragma unroll
    for (int kk = 0; kk < 8; ++kk) {
        bf16x8 a = *(bf16x8*)((char*)lA + ((row * 512 + kk * 64 + kg * 16) ^ ((row & 7) << 4)));
        bf16x8 b = ((const bf16x8*)(Wwb + (size_t)j * 256))[kk * 4 + kg];
        dacc = __builtin_amdgcn_mfma_f32_16x16x32_bf16(a, b, dacc, 0, 0, 0);
    }

    float wb = Wb[j];
    float ss[4];
#pragma unroll
    for (int r = 0; r < 4; ++r) {
        float v = dacc[r] + wb;
        v = v > 0.f ? v : 0.01f * v;
        dacc[r] = v;
        ss[r] = v * v;
    }
#pragma unroll
    for (int r = 0; r < 4; ++r) {
        ss[r] += __shfl_xor(ss[r], 1);
        ss[r] += __shfl_xor(ss[r], 2);
        ss[r] += __shfl_xor(ss[r], 4);
        ss[r] += __shfl_xor(ss[r], 8);
    }
    if (row == 0) {
#pragma unroll
        for (int r = 0; r < 4; ++r) sred[wid][kg * 4 + r] = ss[r];
    }
    __syncthreads();
    float invn[4];
#pragma unroll
    for (int r = 0; r < 4; ++r) {
        float s = 0.f;
#pragma unroll
        for (int w8 = 0; w8 < 8; ++w8) s += sred[w8][kg * 4 + r];
        float n = sqrtf(s);
        invn[r] = (n == 0.f) ? 1.f : 1.f / n;
    }
    if (outf) {
#pragma unroll
        for (int r = 0; r < 4; ++r)
            outf[(size_t)(mbase + kg * 4 + r) * F + j] = dacc[r] * invn[r];
    } else {
#pragma unroll
        for (int r = 0; r < 4; ++r)
            outb[(size_t)(mbase + kg * 4 + r) * F + j] = f2b(dacc[r] * invn[r]);
    }
}

// ---------------- duplicate-row fixup on d_out -------------------------------

__global__ void k_fix(const int* __restrict__ map1, const int* __restrict__ ns1,
                      float* __restrict__ out, int n) {
    int i = blockIdx.x * blockDim.x + threadIdx.x;
    if (i < n) {
        int p = map1[ns1[i]];
        if (p != i) {
            float4* o = (float4*)out;
#pragma unroll
            for (int c = 0; c < 32; ++c) o[(size_t)i * 32 + c] = o[(size_t)p * 32 + c];
        }
    }
}

// ---------------- launcher ---------------------------------------------------

extern "C" void kernel_launch(void* const* d_in, const int* in_sizes, int n_in,
                              void* d_out, int out_size, void* d_ws, size_t ws_size,
                              hipStream_t stream) {
    const float* h    = (const float*)d_in[0];
    const float* Qw0  = (const float*)d_in[1];
    const float* Qb0  = (const float*)d_in[2];
    const float* Ww0  = (const float*)d_in[3];
    const float* Wb0  = (const float*)d_in[4];
    const float* Qw1  = (const float*)d_in[5];
    const float* Qb1  = (const float*)d_in[6];
    const float* Ww1  = (const float*)d_in[7];
    const float* Wb1  = (const float*)d_in[8];
    const int*   ns0  = (const int*)d_in[9];
    const int*   nb0  = (const int*)d_in[10];
    const float* nbw0 = (const float*)d_in[11];
    const int*   ns1  = (const int*)d_in[12];
    const int*   nb1  = (const int*)d_in[13];
    const float* nbw1 = (const float*)d_in[14];

    // ws: map0 | map1 | new0b bf16 | Qw0b | Qw1b | Ww0b | Ww1b
    int* map0 = (int*)d_ws;
    int* map1 = map0 + NN;
    unsigned short* new0b = (unsigned short*)(map1 + NN);
    unsigned short* Qw0b = new0b + (size_t)N0 * F;
    unsigned short* Qw1b = Qw0b + 128 * 128;
    unsigned short* Ww0b = Qw1b + 128 * 128;
    unsigned short* Ww1b = Ww0b + 128 * 256;

    hipMemsetAsync(map0, 0xFF, (size_t)2 * NN * sizeof(int), stream);
    k_prep<<<64, 256, 0, stream>>>(ns0, ns1, map0, map1,
                                   Qw0, Qw1, Ww0, Ww1, Qw0b, Qw1b, Ww0b, Ww1b);

    // layer 0 (reads original h; writes new0 bf16)
    k_layer<<<N0 / 16, 512, 0, stream>>>(h, nullptr, nullptr, ns0, nb0, nbw0,
                                         Qw0b, Qb0, Ww0b, Wb0, nullptr, new0b);

    // layer 1 (h with nodeset0 rows redirected to new0b; writes d_out f32)
    k_layer<<<N1 / 16, 512, 0, stream>>>(h, new0b, map0, ns1, nb1, nbw1,
                                         Qw1b, Qb1, Ww1b, Wb1, (float*)d_out, nullptr);

    k_fix<<<(N1 + 255) / 256, 256, 0, stream>>>(map1, ns1, (float*)d_out, N1);
}